// Round 3
// baseline (249.268 us; speedup 1.0000x reference)
//
#include <hip/hip_runtime.h>
#include <hip/hip_cooperative_groups.h>

namespace cg = cooperative_groups;

// out[b] = (2.0*0.5) * dot(x[b,:], colsum(weight)) — memory-bound, 128 MiB mandatory reads.
// Single cooperative kernel, 3 phases, 2 grid syncs (kills 2 launch gaps + finish dispatch).

#define BATCH 4096
#define ISZ   4096
#define HSZ   4096
#define COL4  (ISZ / 4)        // 1024 float4 columns
#define NBLK  1024             // 4 blocks/CU, co-resident
#define NTHR  256
#define RCH   256              // row chunks (phase 1)
#define ROWS_PER_CHUNK (HSZ / RCH)   // 16
#define SCALE 1.0f

__global__ __launch_bounds__(NTHR, 4) void fused_all(
    const float* __restrict__ x, const float* __restrict__ w,
    float* __restrict__ part, float* __restrict__ wsum,
    float* __restrict__ out) {
    __shared__ float4 wsum_lds[COL4];   // 16 KiB
    __shared__ float4 buf[NTHR];        // 4 KiB (phase 2 tree)
    __shared__ float  redbuf[16];

    const int b = blockIdx.x;
    const int t = threadIdx.x;
    cg::grid_group grid = cg::this_grid();

    // ---- Phase 1: colsum partials. 4 col-tiles x 256 chunks of 16 rows. ----
    {
        const int ct    = b & 3;
        const int chunk = b >> 2;
        const int col4  = ct * 256 + t;
        const float4* w4 = (const float4*)w;
        const size_t r0 = (size_t)chunk * ROWS_PER_CHUNK;
        float4 acc = make_float4(0.f, 0.f, 0.f, 0.f);
        #pragma unroll
        for (int r = 0; r < ROWS_PER_CHUNK; ++r) {
            float4 v = w4[(r0 + r) * COL4 + col4];
            acc.x += v.x; acc.y += v.y; acc.z += v.z; acc.w += v.w;
        }
        ((float4*)part)[(size_t)chunk * COL4 + col4] = acc;
    }
    grid.sync();

    // ---- Phase 2: reduce 256 chunk-partials -> wsum. Blocks 0..255. ----
    if (b < 256) {
        const int col4 = b * 4 + (t & 3);
        const int g    = t >> 2;              // 64 groups x 4 chunks
        const float4* p4 = (const float4*)part;
        float4 acc = make_float4(0.f, 0.f, 0.f, 0.f);
        #pragma unroll
        for (int c = g * 4; c < g * 4 + 4; ++c) {
            float4 v = p4[(size_t)c * COL4 + col4];
            acc.x += v.x; acc.y += v.y; acc.z += v.z; acc.w += v.w;
        }
        buf[t] = acc;
        __syncthreads();
        #pragma unroll
        for (int s = 32; s >= 1; s >>= 1) {
            if (g < s) {
                float4 o = buf[t + 4 * s];
                acc.x += o.x; acc.y += o.y; acc.z += o.z; acc.w += o.w;
                buf[t] = acc;
            }
            __syncthreads();
        }
        if (g == 0) ((float4*)wsum)[col4] = buf[t];
    }
    grid.sync();

    // ---- Phase 3: rowdot, 4 rows per block, wsum staged in LDS. ----
    {
        const float4* s4 = (const float4*)wsum;
        #pragma unroll
        for (int k = 0; k < 4; ++k) wsum_lds[k * NTHR + t] = s4[k * NTHR + t];
        __syncthreads();

        const int r0 = b * 4;
        const float4* x4 = (const float4*)x;
        float acc[4];
        #pragma unroll
        for (int k = 0; k < 4; ++k) {
            acc[k] = 0.f;
            const size_t base = (size_t)(r0 + k) * COL4;
            #pragma unroll
            for (int it = 0; it < 4; ++it) {
                const int idx = it * NTHR + t;
                float4 xv = x4[base + idx];
                float4 sv = wsum_lds[idx];
                acc[k] += xv.x * sv.x + xv.y * sv.y + xv.z * sv.z + xv.w * sv.w;
            }
        }
        const int wave = t >> 6;
        #pragma unroll
        for (int k = 0; k < 4; ++k) {
            float a = acc[k];
            #pragma unroll
            for (int off = 32; off > 0; off >>= 1)
                a += __shfl_down(a, off, 64);
            if ((t & 63) == 0) redbuf[k * 4 + wave] = a;
        }
        __syncthreads();
        if (t < 4)
            out[r0 + t] = SCALE * (redbuf[t * 4 + 0] + redbuf[t * 4 + 1] +
                                   redbuf[t * 4 + 2] + redbuf[t * 4 + 3]);
    }
}

// ---- Fallback path (plain 3-kernel) in case cooperative launch is refused ----
__global__ __launch_bounds__(256) void colsum_partial_fb(
    const float* __restrict__ w, float* __restrict__ part) {
    const int col4  = blockIdx.x * 256 + threadIdx.x;
    const int chunk = blockIdx.y;
    const float4* w4 = (const float4*)w;
    const size_t r0 = (size_t)chunk * ROWS_PER_CHUNK;
    float4 acc = make_float4(0.f, 0.f, 0.f, 0.f);
    #pragma unroll
    for (int r = 0; r < ROWS_PER_CHUNK; ++r) {
        float4 v = w4[(r0 + r) * COL4 + col4];
        acc.x += v.x; acc.y += v.y; acc.z += v.z; acc.w += v.w;
    }
    ((float4*)part)[(size_t)chunk * COL4 + col4] = acc;
}

__global__ __launch_bounds__(256) void colsum_finish_fb(
    const float* __restrict__ part, float* __restrict__ wsum) {
    __shared__ float4 buf[256];
    const int t    = threadIdx.x;
    const int col4 = blockIdx.x * 4 + (t & 3);
    const int g    = t >> 2;
    const float4* p4 = (const float4*)part;
    float4 acc = make_float4(0.f, 0.f, 0.f, 0.f);
    #pragma unroll
    for (int c = g * 4; c < g * 4 + 4; ++c) {
        float4 v = p4[(size_t)c * COL4 + col4];
        acc.x += v.x; acc.y += v.y; acc.z += v.z; acc.w += v.w;
    }
    buf[t] = acc;
    __syncthreads();
    #pragma unroll
    for (int s = 32; s >= 1; s >>= 1) {
        if (g < s) {
            float4 o = buf[t + 4 * s];
            acc.x += o.x; acc.y += o.y; acc.z += o.z; acc.w += o.w;
            buf[t] = acc;
        }
        __syncthreads();
    }
    if (g == 0) ((float4*)wsum)[col4] = buf[t];
}

__global__ __launch_bounds__(256) void rowdot_fb(
    const float* __restrict__ x, const float* __restrict__ wsum,
    float* __restrict__ out) {
    const int b   = blockIdx.x;
    const int tid = threadIdx.x;
    const float4* x4 = (const float4*)(x + (size_t)b * ISZ);
    const float4* s4 = (const float4*)wsum;
    float acc = 0.f;
    #pragma unroll
    for (int it = 0; it < 4; ++it) {
        const int idx = it * 256 + tid;
        float4 xv = x4[idx];
        float4 sv = s4[idx];
        acc += xv.x * sv.x + xv.y * sv.y + xv.z * sv.z + xv.w * sv.w;
    }
    #pragma unroll
    for (int off = 32; off > 0; off >>= 1)
        acc += __shfl_down(acc, off, 64);
    __shared__ float red[4];
    const int wave = tid >> 6;
    if ((tid & 63) == 0) red[wave] = acc;
    __syncthreads();
    if (tid == 0) out[b] = SCALE * (red[0] + red[1] + red[2] + red[3]);
}

extern "C" void kernel_launch(void* const* d_in, const int* in_sizes, int n_in,
                              void* d_out, int out_size, void* d_ws, size_t ws_size,
                              hipStream_t stream) {
    const float* x = (const float*)d_in[0];   // [BATCH, ISZ]
    const float* w = (const float*)d_in[1];   // [HSZ, ISZ]
    float* out = (float*)d_out;

    float* part = (float*)d_ws;                         // RCH * ISZ f32 = 4 MiB
    float* wsum = (float*)d_ws + (size_t)RCH * ISZ;     // 16 KiB

    void* args[] = { (void*)&x, (void*)&w, (void*)&part, (void*)&wsum, (void*)&out };
    hipError_t err = hipLaunchCooperativeKernel((void*)fused_all,
                                                dim3(NBLK), dim3(NTHR),
                                                args, 0, stream);
    if (err != hipSuccess) {
        // Fallback: plain 3-kernel path.
        colsum_partial_fb<<<dim3(4, RCH), 256, 0, stream>>>(w, part);
        colsum_finish_fb<<<dim3(256), 256, 0, stream>>>(part, wsum);
        rowdot_fb<<<dim3(BATCH), 256, 0, stream>>>(x, wsum, out);
    }
}

// Round 5
// 42.588 us; speedup vs baseline: 5.8530x; 5.8530x over previous
//
#include <hip/hip_runtime.h>

// out[b] = (2.0*0.5) * dot(x[b,:], colsum(weight)) — 128 MiB mandatory reads.
// K1: colsum with in-kernel distributed finish (flag-based, 256 co-resident blocks).
// K2: per-row dot. One inter-kernel gap total.

typedef float f4 __attribute__((ext_vector_type(4)));  // native vec for nontemporal builtins

#define BATCH 4096
#define ISZ   4096
#define HSZ   4096
#define COL4  (ISZ / 4)     // 1024 float4 columns
#define NCT   16            // col tiles of 64 float4 each
#define NCH   16            // row chunks of 256 rows each
#define MAGIC 0x5A5A5A5Au   // != 0xAAAAAAAA poison, != 0
#define SCALE 1.0f

// K1: grid (NCT, NCH) = 256 blocks, 256 threads. Block (ct,c): cols [ct*64,ct*64+64)
// float4, rows [c*256, c*256+256). Wave g handles 64 rows; LDS-reduce 4 waves.
// Block (ct, 15) additionally finishes col-tile ct once all 16 chunk flags are set.
__global__ __launch_bounds__(256) void colsum_fused(
    const float* __restrict__ w, float* __restrict__ part,
    float* __restrict__ wsum, unsigned int* flags) {
    __shared__ f4 buf[4][64];
    const int t    = threadIdx.x;
    const int ct   = blockIdx.x;       // 0..15
    const int c    = blockIdx.y;       // 0..15
    const int lane = t & 63;
    const int g    = t >> 6;           // wave 0..3
    const int col4 = ct * 64 + lane;
    const f4* w4 = (const f4*)w;

    // ---- streaming partial: 64 rows per thread-group, 1 KiB contiguous per wave-load ----
    f4 acc = (f4)(0.f);
    const size_t r0 = (size_t)c * 256 + (size_t)g * 64;
    #pragma unroll 8
    for (int k = 0; k < 64; ++k) {
        f4 v = __builtin_nontemporal_load(&w4[(r0 + k) * COL4 + col4]);
        acc += v;
    }
    buf[g][lane] = acc;
    __syncthreads();
    if (g == 0) {
        f4 a = buf[0][lane] + buf[1][lane] + buf[2][lane] + buf[3][lane];
        ((f4*)part)[(size_t)c * COL4 + col4] = a;
    }
    __syncthreads();                    // drains wave-0 part store before flag set
    if (t == 0) {
        __threadfence();                // agent-scope release (L2 writeback)
        __hip_atomic_store(&flags[ct * NCH + c], MAGIC,
                           __ATOMIC_RELEASE, __HIP_MEMORY_SCOPE_AGENT);
    }

    if (c != NCH - 1) return;

    // ---- finisher for col-tile ct: wait for 16 flags, reduce 16 KiB ----
    if (t == 0) {
        for (int cc = 0; cc < NCH; ++cc) {
            while (__hip_atomic_load(&flags[ct * NCH + cc],
                                     __ATOMIC_ACQUIRE, __HIP_MEMORY_SCOPE_AGENT) != MAGIC)
                __builtin_amdgcn_s_sleep(1);
        }
        __threadfence();                // acquire side
    }
    __syncthreads();

    f4 acc2 = (f4)(0.f);
    #pragma unroll
    for (int q = 0; q < 4; ++q) {
        const int cc = g * 4 + q;
        acc2 += ((const f4*)part)[(size_t)cc * COL4 + col4];
    }
    buf[g][lane] = acc2;
    __syncthreads();
    if (g == 0) {
        f4 a = buf[0][lane] + buf[1][lane] + buf[2][lane] + buf[3][lane];
        ((f4*)wsum)[col4] = a;
    }
    // reset flags for next replay (poison-proof: any value != MAGIC is "not done")
    if (t < NCH)
        __hip_atomic_store(&flags[ct * NCH + t], 0u,
                           __ATOMIC_RELAXED, __HIP_MEMORY_SCOPE_AGENT);
}

// K2: grid = BATCH, block = 256. out[b] = SCALE * dot(x[b], wsum). (R1-proven form)
__global__ __launch_bounds__(256) void rowdot(
    const float* __restrict__ x, const float* __restrict__ wsum,
    float* __restrict__ out) {
    const int b   = blockIdx.x;
    const int tid = threadIdx.x;
    const f4* x4 = (const f4*)(x + (size_t)b * ISZ);
    const f4* s4 = (const f4*)wsum;
    float acc = 0.f;
    #pragma unroll
    for (int it = 0; it < 4; ++it) {
        const int idx = it * 256 + tid;
        f4 xv = __builtin_nontemporal_load(&x4[idx]);
        f4 sv = s4[idx];
        acc += xv.x * sv.x + xv.y * sv.y + xv.z * sv.z + xv.w * sv.w;
    }
    #pragma unroll
    for (int off = 32; off > 0; off >>= 1)
        acc += __shfl_down(acc, off, 64);
    __shared__ float red[4];
    const int wave = tid >> 6;
    if ((tid & 63) == 0) red[wave] = acc;
    __syncthreads();
    if (tid == 0) out[b] = SCALE * (red[0] + red[1] + red[2] + red[3]);
}

extern "C" void kernel_launch(void* const* d_in, const int* in_sizes, int n_in,
                              void* d_out, int out_size, void* d_ws, size_t ws_size,
                              hipStream_t stream) {
    const float* x = (const float*)d_in[0];   // [BATCH, ISZ]
    const float* w = (const float*)d_in[1];   // [HSZ, ISZ]
    float* out = (float*)d_out;

    float* part = (float*)d_ws;                                   // NCH*ISZ f32 = 256 KiB
    float* wsum = part + (size_t)NCH * ISZ;                       // 16 KiB
    unsigned int* flags = (unsigned int*)(wsum + ISZ);            // NCT*NCH u32 = 1 KiB

    colsum_fused<<<dim3(NCT, NCH), 256, 0, stream>>>(w, part, wsum, flags);
    rowdot<<<dim3(BATCH), 256, 0, stream>>>(x, wsum, out);
}